// Round 2
// baseline (1706.630 us; speedup 1.0000x reference)
//
#include <hip/hip_runtime.h>
#include <hip/hip_bf16.h>

// Problem: T=256, B=128, DIN=20, H=1024, OUT=1095, L=3
//   h = x @ W1 + b1                       (T*B,20)x(20,1024)
//   3x SRU: U = h @ W_sru[l]  (T*B,1024)x(1024,3072); gates z|f|r
//           scan over T: c = f*c + (1-f)*z ; h = r*c + (1-r)*h_in
//   out = h @ W3 + b3                     (T*B,1024)x(1024,1095)
// ALL harness tensors are fp32 (reference is float32). We convert weights/h
// to bf16 internally for MFMA, accumulate fp32, carry c in fp32, output fp32.

#define T_DIM 256
#define B_DIM 128
#define DIN 20
#define H_DIM 1024
#define OUT_DIM 1095
#define L_DIM 3
#define M_DIM (T_DIM * B_DIM)        // 32768
#define H3 (3 * H_DIM)               // 3072
#define TCH 64                        // T-chunk for SRU (4 chunks)
#define MCH (TCH * B_DIM)            // 8192 rows per chunk
#define OUT_ELEMS ((size_t)M_DIM * OUT_DIM)   // 35,880,960

typedef __bf16 bf16x8 __attribute__((ext_vector_type(8)));
typedef __bf16 bf16x2 __attribute__((ext_vector_type(2)));
typedef float f32x4 __attribute__((ext_vector_type(4)));

__device__ __forceinline__ void async16(const __bf16* g, __bf16* l) {
  __builtin_amdgcn_global_load_lds(
      (const __attribute__((address_space(1))) void*)g,
      (__attribute__((address_space(3))) void*)l, 16, 0, 0);
}

// ---- transpose + cast W_sru (L,H,3H) fp32 -> (L,3H,H) bf16 ----
__global__ void transpose_sru(const float* __restrict__ W, __bf16* __restrict__ Wt) {
  __shared__ float tile[32][33];
  int l = blockIdx.z;
  int j0 = blockIdx.x * 32;  // col within 3H
  int i0 = blockIdx.y * 32;  // row within H
  int tx = threadIdx.x, ty = threadIdx.y;  // 32x8
  const float* Wl = W + (size_t)l * H_DIM * H3;
  __bf16* Wtl = Wt + (size_t)l * H_DIM * H3;
#pragma unroll
  for (int r = 0; r < 4; r++)
    tile[ty + r * 8][tx] = Wl[(size_t)(i0 + ty + r * 8) * H3 + j0 + tx];
  __syncthreads();
#pragma unroll
  for (int r = 0; r < 4; r++)
    Wtl[(size_t)(j0 + ty + r * 8) * H_DIM + i0 + tx] = (__bf16)tile[tx][ty + r * 8];
}

// ---- transpose + cast W3 (H,OUT) fp32 -> (OUT,H) bf16, OUT=1095 edge ----
__global__ void transpose_w3(const float* __restrict__ W, __bf16* __restrict__ Wt) {
  __shared__ float tile[32][33];
  int j0 = blockIdx.x * 32;  // col within OUT
  int i0 = blockIdx.y * 32;  // row within H
  int tx = threadIdx.x, ty = threadIdx.y;
#pragma unroll
  for (int r = 0; r < 4; r++) {
    int j = j0 + tx;
    if (j < OUT_DIM)
      tile[ty + r * 8][tx] = W[(size_t)(i0 + ty + r * 8) * OUT_DIM + j];
  }
  __syncthreads();
#pragma unroll
  for (int r = 0; r < 4; r++) {
    int j = j0 + ty + r * 8;
    if (j < OUT_DIM)
      Wt[(size_t)j * H_DIM + i0 + tx] = (__bf16)tile[tx][ty + r * 8];
  }
}

// ---- dense1: h = x @ W1 + b1 ; x (M,20) fp32, W1 (20,1024) fp32 -> h bf16 ----
__global__ __launch_bounds__(256) void dense1(const float* __restrict__ x,
                                              const float* __restrict__ W1,
                                              const float* __restrict__ b1,
                                              __bf16* __restrict__ h) {
  __shared__ float wsl[DIN * 256];
  __shared__ float xs[128 * DIN];
  int tid = threadIdx.x;
  int m0 = blockIdx.x * 128;
  int n0 = blockIdx.y * 256;
#pragma unroll
  for (int k = 0; k < DIN; k++) wsl[k * 256 + tid] = W1[k * H_DIM + n0 + tid];
  for (int idx = tid; idx < 128 * DIN; idx += 256) xs[idx] = x[(size_t)m0 * DIN + idx];
  __syncthreads();
  float wreg[DIN];
#pragma unroll
  for (int k = 0; k < DIN; k++) wreg[k] = wsl[k * 256 + tid];
  float bias = b1[n0 + tid];
  for (int m = 0; m < 128; m++) {
    float acc = bias;
#pragma unroll
    for (int k = 0; k < DIN; k++) acc += xs[m * DIN + k] * wreg[k];
    h[(size_t)(m0 + m) * H_DIM + n0 + tid] = (__bf16)acc;
  }
}

// ---- MFMA GEMM: C = A(Mx1024)bf16 * Bt(Nx1024)bf16^T, m97 structure ----
// EPI 0: bias + predicated fp32 store (output GEMM, N=1095)
// EPI 1: SRU gates bf16 store: z passthrough, f/r sigmoid(+bias)
template <int EPI>
__global__ __launch_bounds__(256) void gemm_bt(const __bf16* __restrict__ A,
                                               const __bf16* __restrict__ Bt,
                                               void* __restrict__ Cv,
                                               const float* __restrict__ bias0,
                                               const float* __restrict__ bias1,
                                               int Ntotal, int ldc) {
  constexpr int K = 1024;
  __shared__ __align__(16) __bf16 sA[128 * 32];
  __shared__ __align__(16) __bf16 sB[128 * 32];
  int tid = threadIdx.x;
  int lane = tid & 63;
  int wave = tid >> 6;
  int wm = wave & 1, wn = wave >> 1;
  int m0 = blockIdx.x * 128;
  int n0 = blockIdx.y * 128;

  f32x4 acc[4][4];
#pragma unroll
  for (int i = 0; i < 4; i++)
#pragma unroll
    for (int j = 0; j < 4; j++) acc[i][j] = (f32x4)0.f;

  int lrow = lane >> 2;          // 0..15
  int lcol8 = (lane & 3) * 8;    // 0,8,16,24 elements
  int q8 = (lane >> 4) * 8;
  int l15 = lane & 15;

  for (int k0 = 0; k0 < K; k0 += 32) {
    __syncthreads();
#pragma unroll
    for (int i = 0; i < 2; i++) {
      int j = wave * 2 + i;
      int arow = m0 + j * 16 + lrow;
      async16(A + (size_t)arow * K + k0 + lcol8, &sA[j * 512]);
      int brow = n0 + j * 16 + lrow;
      if (EPI == 0) brow = brow < Ntotal - 1 ? brow : Ntotal - 1;
      async16(Bt + (size_t)brow * K + k0 + lcol8, &sB[j * 512]);
    }
    __syncthreads();
    bf16x8 aF[4], bF[4];
#pragma unroll
    for (int i = 0; i < 4; i++) {
      aF[i] = *(const bf16x8*)&sA[(wm * 64 + i * 16 + l15) * 32 + q8];
      bF[i] = *(const bf16x8*)&sB[(wn * 64 + i * 16 + l15) * 32 + q8];
    }
#pragma unroll
    for (int mi = 0; mi < 4; mi++)
#pragma unroll
      for (int ni = 0; ni < 4; ni++)
        acc[mi][ni] = __builtin_amdgcn_mfma_f32_16x16x32_bf16(aF[mi], bF[ni], acc[mi][ni], 0, 0, 0);
  }

  int quad = lane >> 4;
#pragma unroll
  for (int mi = 0; mi < 4; mi++) {
    int rowBase = m0 + wm * 64 + mi * 16 + quad * 4;
#pragma unroll
    for (int ni = 0; ni < 4; ni++) {
      int colBase = n0 + wn * 64 + ni * 16;
      int col = colBase + l15;
      if (EPI == 1) {
        __bf16* C = (__bf16*)Cv;
        int gate = colBase >> 10;  // 0=z, 1=f, 2=r (128-tile never straddles)
        float badd = 0.f;
        if (gate == 1) badd = bias0[col - 1024];
        else if (gate == 2) badd = bias1[col - 2048];
#pragma unroll
        for (int r = 0; r < 4; r++) {
          float v = acc[mi][ni][r];
          if (gate != 0) v = 1.f / (1.f + __expf(-(v + badd)));
          C[(size_t)(rowBase + r) * ldc + col] = (__bf16)v;
        }
      } else {
        float* C = (float*)Cv;
        if (col < Ntotal) {
          float badd = bias0[col];
#pragma unroll
          for (int r = 0; r < 4; r++)
            C[(size_t)(rowBase + r) * ldc + col] = acc[mi][ni][r] + badd;
        }
      }
    }
  }
}

// ---- SRU scan over a T-chunk; h updated in place; c carried fp32 in ws ----
__global__ __launch_bounds__(256) void sru_scan(const __bf16* __restrict__ U,
                                                __bf16* __restrict__ h,
                                                float* __restrict__ cst,
                                                float* __restrict__ cfin,
                                                int tc, int first, int last) {
  int id = blockIdx.x * 256 + threadIdx.x;  // 0..65535 (B*H/2)
  int n2 = id * 2;
  int b = n2 >> 10;
  int hh = n2 & 1023;
  float c0, c1;
  if (first) { c0 = 0.f; c1 = 0.f; }
  else { c0 = cst[n2]; c1 = cst[n2 + 1]; }
  size_t ub = (size_t)b * H3 + hh;
  size_t xb = (size_t)b * H_DIM + hh;
  const size_t strideU = (size_t)B_DIM * H3;
  const size_t strideH = (size_t)B_DIM * H_DIM;
  for (int t = 0; t < tc; t++) {
    bf16x2 z2 = *(const bf16x2*)&U[ub];
    bf16x2 f2 = *(const bf16x2*)&U[ub + 1024];
    bf16x2 r2 = *(const bf16x2*)&U[ub + 2048];
    bf16x2 x2 = *(const bf16x2*)&h[xb];
    float f0 = (float)f2[0], f1 = (float)f2[1];
    float r0 = (float)r2[0], r1 = (float)r2[1];
    c0 = f0 * c0 + (1.f - f0) * (float)z2[0];
    c1 = f1 * c1 + (1.f - f1) * (float)z2[1];
    float h0 = r0 * c0 + (1.f - r0) * (float)x2[0];
    float h1 = r1 * c1 + (1.f - r1) * (float)x2[1];
    bf16x2 o;
    o[0] = (__bf16)h0;
    o[1] = (__bf16)h1;
    *(bf16x2*)&h[xb] = o;
    ub += strideU;
    xb += strideH;
  }
  cst[n2] = c0;
  cst[n2 + 1] = c1;
  if (last) {
    cfin[n2] = c0;
    cfin[n2 + 1] = c1;
  }
}

extern "C" void kernel_launch(void* const* d_in, const int* in_sizes, int n_in,
                              void* d_out, int out_size, void* d_ws, size_t ws_size,
                              hipStream_t stream) {
  const float* x = (const float*)d_in[0];
  // d_in[1] = c (unused by reference)
  const float* W1 = (const float*)d_in[2];
  const float* b1 = (const float*)d_in[3];
  const float* Wsru = (const float*)d_in[4];
  const float* bf_s = (const float*)d_in[5];
  const float* br_s = (const float*)d_in[6];
  const float* W3 = (const float*)d_in[7];
  const float* b3 = (const float*)d_in[8];
  float* out = (float*)d_out;

  // workspace layout (bytes)
  char* wsb = (char*)d_ws;
  __bf16* h = (__bf16*)(wsb);                                   // 32768*1024*2   = 67,108,864
  __bf16* U = (__bf16*)(wsb + 67108864);                        //  8192*3072*2   = 50,331,648
  __bf16* Wt = (__bf16*)(wsb + 67108864 + 50331648);            // 3*3072*1024*2  = 18,874,368
  __bf16* W3t = (__bf16*)(wsb + 67108864 + 50331648 + 18874368);// 1095*1024*2    =  2,242,560
  float* cst = (float*)(wsb + 67108864 + 50331648 + 18874368 + 2242560); // 131072*4

  transpose_sru<<<dim3(H3 / 32, H_DIM / 32, L_DIM), dim3(32, 8), 0, stream>>>(Wsru, Wt);
  transpose_w3<<<dim3((OUT_DIM + 31) / 32, H_DIM / 32), dim3(32, 8), 0, stream>>>(W3, W3t);
  dense1<<<dim3(M_DIM / 128, H_DIM / 256), 256, 0, stream>>>(x, W1, b1, h);

  for (int l = 0; l < L_DIM; l++) {
    const __bf16* Wtl = Wt + (size_t)l * H_DIM * H3;
    const float* bfl = bf_s + l * H_DIM;
    const float* brl = br_s + l * H_DIM;
    float* cfin = out + OUT_ELEMS + (size_t)l * B_DIM * H_DIM;
    for (int ch = 0; ch < T_DIM / TCH; ch++) {
      __bf16* hA = h + (size_t)ch * MCH * H_DIM;
      gemm_bt<1><<<dim3(MCH / 128, H3 / 128), 256, 0, stream>>>(hA, Wtl, U, bfl, brl, H3, H3);
      sru_scan<<<dim3(B_DIM * H_DIM / 512), 256, 0, stream>>>(
          U, hA, cst, cfin, TCH, ch == 0 ? 1 : 0, ch == (T_DIM / TCH - 1) ? 1 : 0);
    }
  }

  gemm_bt<0><<<dim3(M_DIM / 128, (OUT_DIM + 127) / 128), 256, 0, stream>>>(
      h, W3t, out, b3, nullptr, OUT_DIM, OUT_DIM);
}